// Round 1
// baseline (1244.420 us; speedup 1.0000x reference)
//
#include <hip/hip_runtime.h>

// Problem constants
#define B_    32
#define T_    2048
#define F_    768
#define H_    12
#define DH_   64
#define MTOK  (B_*T_)     // 65536
#define NQKV  (3*F_)      // 2304

typedef __bf16 bf16;
typedef __bf16 bf16x8 __attribute__((ext_vector_type(8)));
typedef float  f32x4  __attribute__((ext_vector_type(4)));

// ---------------------------------------------------------------- helpers
__device__ __forceinline__ void gload_lds16(const bf16* g, bf16* l) {
  __builtin_amdgcn_global_load_lds(
      (const __attribute__((address_space(1))) unsigned*)g,
      (__attribute__((address_space(3))) unsigned*)l, 16, 0, 0);
}

// ---------------------------------------------------------------- casts
__global__ void k_cast_x(const float* __restrict__ in, bf16* __restrict__ out, int n8) {
  int i = blockIdx.x * 256 + threadIdx.x;
  if (i >= n8) return;
  const float4* p = (const float4*)in + (size_t)i * 2;
  float4 f0 = p[0], f1 = p[1];
  bf16x8 o;
  o[0]=(bf16)f0.x; o[1]=(bf16)f0.y; o[2]=(bf16)f0.z; o[3]=(bf16)f0.w;
  o[4]=(bf16)f1.x; o[5]=(bf16)f1.y; o[6]=(bf16)f1.z; o[7]=(bf16)f1.w;
  *((bf16x8*)out + i) = o;
}

// out[n][k] = (bf16) in[k][n]   (pre-transpose W so GEMM B-tiles stage linearly)
__global__ void k_tcast(const float* __restrict__ in, bf16* __restrict__ out, int K, int N) {
  __shared__ float tile[32][33];
  int n0 = blockIdx.x * 32, k0 = blockIdx.y * 32;
  int tx = threadIdx.x & 31, ty = threadIdx.x >> 5;   // 8 rows, loop 4
#pragma unroll
  for (int r = 0; r < 4; ++r)
    tile[ty + r*8][tx] = in[(size_t)(k0 + ty + r*8) * N + n0 + tx];
  __syncthreads();
#pragma unroll
  for (int r = 0; r < 4; ++r)
    out[(size_t)(n0 + ty + r*8) * K + k0 + tx] = (bf16)tile[tx][ty + r*8];
}

// ---------------------------------------------------------------- m97-style GEMM
// C[M][N] = A[M][K] * Bt[N][K]^T + bias[N].   128x128 tile, BK=32, 4 waves.
template <typename OutT>
__global__ void k_gemm_bt(const bf16* __restrict__ A, const bf16* __restrict__ Bt,
                          const float* __restrict__ bias, OutT* __restrict__ C,
                          int M, int N, int K, int Mt) {
  __shared__ bf16 As[128 * 32];
  __shared__ bf16 Bs[128 * 32];
  int nwg = gridDim.x;
  int bid = blockIdx.x;
  int swz = (bid & 7) * (nwg >> 3) + (bid >> 3);       // XCD swizzle (nwg % 8 == 0)
  int bm = swz % Mt, bn = swz / Mt;
  int tid = threadIdx.x, wv = tid >> 6, l = tid & 63;
  int wm = (wv >> 1) * 64, wn = (wv & 1) * 64;
  f32x4 acc[4][4] = {};
  const bf16* Ab = A + (size_t)(bm * 128) * K;
  const bf16* Bb = Bt + (size_t)(bn * 128) * K;
  int srow = l >> 2;              // 0..15
  int scol = (l & 3) * 8;
  const int nk = K >> 5;
  for (int kt = 0; kt < nk; ++kt) {
    int k0 = kt * 32;
    __syncthreads();
#pragma unroll
    for (int i = 0; i < 2; ++i) {
      int rr = (i * 4 + wv) * 16 + srow;
      gload_lds16(Ab + (size_t)rr * K + k0 + scol, As + (i * 4 + wv) * 512);
      gload_lds16(Bb + (size_t)rr * K + k0 + scol, Bs + (i * 4 + wv) * 512);
    }
    __syncthreads();
    bf16x8 af[4], bfr[4];
#pragma unroll
    for (int t = 0; t < 4; ++t) {
      af[t]  = *(const bf16x8*)&As[(wm + t * 16 + (l & 15)) * 32 + (l >> 4) * 8];
      bfr[t] = *(const bf16x8*)&Bs[(wn + t * 16 + (l & 15)) * 32 + (l >> 4) * 8];
    }
#pragma unroll
    for (int mi = 0; mi < 4; ++mi)
#pragma unroll
      for (int ni = 0; ni < 4; ++ni)
        acc[mi][ni] = __builtin_amdgcn_mfma_f32_16x16x32_bf16(af[mi], bfr[ni], acc[mi][ni], 0, 0, 0);
  }
#pragma unroll
  for (int ni = 0; ni < 4; ++ni) {
    int col = bn * 128 + wn + ni * 16 + (l & 15);
    float bv = bias[col];
#pragma unroll
    for (int mi = 0; mi < 4; ++mi)
#pragma unroll
      for (int r = 0; r < 4; ++r) {
        int row = bm * 128 + wm + mi * 16 + (l >> 4) * 4 + r;
        C[(size_t)row * N + col] = (OutT)(acc[mi][ni][r] + bv);
      }
  }
}

// ---------------------------------------------------------------- stage 2: S partials
// S[d][e] = sum_t q[t,d] k[t,e], split over 4 t-ranges for occupancy.
__global__ void k_stage2_partial(const bf16* __restrict__ qkv, float* __restrict__ Spart) {
  int bid = blockIdx.x;
  int part = bid & 3, bh = bid >> 2;
  int b = bh / H_, h = bh % H_;
  __shared__ float qs[64][68];   // +4 pad kills stride-64 bank conflicts
  __shared__ float ks[64][68];
  int tid = threadIdx.x;
  int d0 = (tid >> 4) * 4, e0 = (tid & 15) * 4;
  int sr = tid >> 2, sc = (tid & 3) * 16;
  const bf16* qb = qkv + (size_t)b * T_ * NQKV + h * DH_;
  const bf16* kb = qb + F_;
  float acc[4][4] = {};
  for (int tc = part * 512; tc < part * 512 + 512; tc += 64) {
    __syncthreads();
    bf16x8 qv0 = *(const bf16x8*)&qb[(size_t)(tc + sr) * NQKV + sc];
    bf16x8 qv1 = *(const bf16x8*)&qb[(size_t)(tc + sr) * NQKV + sc + 8];
    bf16x8 kv0 = *(const bf16x8*)&kb[(size_t)(tc + sr) * NQKV + sc];
    bf16x8 kv1 = *(const bf16x8*)&kb[(size_t)(tc + sr) * NQKV + sc + 8];
#pragma unroll
    for (int j = 0; j < 8; ++j) {
      qs[sr][sc + j] = (float)qv0[j]; qs[sr][sc + 8 + j] = (float)qv1[j];
      ks[sr][sc + j] = (float)kv0[j]; ks[sr][sc + 8 + j] = (float)kv1[j];
    }
    __syncthreads();
#pragma unroll 4
    for (int t = 0; t < 64; ++t) {
      f32x4 q4 = *(const f32x4*)&qs[t][d0];
      f32x4 k4 = *(const f32x4*)&ks[t][e0];
#pragma unroll
      for (int i = 0; i < 4; ++i)
#pragma unroll
        for (int j = 0; j < 4; ++j)
          acc[i][j] = fmaf(q4[i], k4[j], acc[i][j]);
    }
  }
  float* Sp = Spart + (size_t)(part * 384 + bh) * 4096;
#pragma unroll
  for (int i = 0; i < 4; ++i)
#pragma unroll
    for (int j = 0; j < 4; ++j)
      Sp[(d0 + i) * 64 + e0 + j] = acc[i][j];
}

// reduce partials, apply /8, causal mask (-10000), fold /64^4, cast bf16
__global__ void k_stage2_finish(const float* __restrict__ Spart, bf16* __restrict__ S2b) {
  int bh = blockIdx.x;
  const float sc_keep = 0.125f / 16777216.0f;      // (1/sqrt(64)) / 64^4
  const float sc_mask = -10000.0f / 16777216.0f;
  for (int i = threadIdx.x; i < 4096; i += 256) {
    int d = i >> 6, e = i & 63;
    float s = 0.f;
#pragma unroll
    for (int p = 0; p < 4; ++p) s += Spart[(size_t)(p * 384 + bh) * 4096 + i];
    float v = (e <= d) ? s * sc_keep : sc_mask;
    S2b[(size_t)bh * 4096 + i] = (bf16)v;
  }
}

// ---------------------------------------------------------------- stage 3
// y[t][d] = sum_e v[t,e] S2[d,e]  (MFMA, A=v, B=S2^T), +mask[b,t], softmax over t
// per d, then w_out (f32) and a_pre = v*w (bf16).  Two-pass recompute, fused.
__global__ __launch_bounds__(256) void k_stage3(const bf16* __restrict__ qkv,
                                                const bf16* __restrict__ S2b,
                                                const float* __restrict__ mask,
                                                float* __restrict__ w_out,
                                                bf16* __restrict__ a_pre) {
  int bh = blockIdx.x;
  int b = bh / H_, h = bh % H_;
  int tid = threadIdx.x, wv = tid >> 6, l = tid & 63;
  const bf16* S2 = S2b + (size_t)bh * 4096;
  bf16x8 sfrag[2][4];
#pragma unroll
  for (int ks = 0; ks < 2; ++ks)
#pragma unroll
    for (int n = 0; n < 4; ++n)
      sfrag[ks][n] = *(const bf16x8*)&S2[(n * 16 + (l & 15)) * 64 + ks * 32 + (l >> 4) * 8];
  const bf16* vb = qkv + (size_t)b * T_ * NQKV + 2 * F_ + h * DH_;
  const float* mb = mask + (size_t)b * T_;
  int t_lo = wv * 512;

  // pass 1: sum of exp per d
  float se[4] = {0.f, 0.f, 0.f, 0.f};
  for (int t0 = t_lo; t0 < t_lo + 512; t0 += 16) {
    f32x4 acc[4] = {};
    bf16x8 a0 = *(const bf16x8*)&vb[(size_t)(t0 + (l & 15)) * NQKV + (l >> 4) * 8];
    bf16x8 a1 = *(const bf16x8*)&vb[(size_t)(t0 + (l & 15)) * NQKV + 32 + (l >> 4) * 8];
#pragma unroll
    for (int n = 0; n < 4; ++n) {
      acc[n] = __builtin_amdgcn_mfma_f32_16x16x32_bf16(a0, sfrag[0][n], acc[n], 0, 0, 0);
      acc[n] = __builtin_amdgcn_mfma_f32_16x16x32_bf16(a1, sfrag[1][n], acc[n], 0, 0, 0);
    }
    float4 mv = *(const float4*)&mb[t0 + (l >> 4) * 4];
    float mr[4] = {mv.x, mv.y, mv.z, mv.w};
#pragma unroll
    for (int n = 0; n < 4; ++n)
#pragma unroll
      for (int r = 0; r < 4; ++r)
        se[n] += __expf(acc[n][r] + mr[r]);
  }
#pragma unroll
  for (int n = 0; n < 4; ++n) {
    se[n] += __shfl_xor(se[n], 16, 64);
    se[n] += __shfl_xor(se[n], 32, 64);
  }
  __shared__ float sred[4][64];
  __shared__ float inv[64];
  if (l < 16) {
#pragma unroll
    for (int n = 0; n < 4; ++n) sred[wv][n * 16 + l] = se[n];
  }
  __syncthreads();
  if (tid < 64) inv[tid] = 1.0f / (sred[0][tid] + sred[1][tid] + sred[2][tid] + sred[3][tid]);
  __syncthreads();
  float iv[4];
#pragma unroll
  for (int n = 0; n < 4; ++n) iv[n] = inv[n * 16 + (l & 15)];

  // pass 2: recompute y, write w and a_pre
  for (int t0 = t_lo; t0 < t_lo + 512; t0 += 16) {
    f32x4 acc[4] = {};
    bf16x8 a0 = *(const bf16x8*)&vb[(size_t)(t0 + (l & 15)) * NQKV + (l >> 4) * 8];
    bf16x8 a1 = *(const bf16x8*)&vb[(size_t)(t0 + (l & 15)) * NQKV + 32 + (l >> 4) * 8];
#pragma unroll
    for (int n = 0; n < 4; ++n) {
      acc[n] = __builtin_amdgcn_mfma_f32_16x16x32_bf16(a0, sfrag[0][n], acc[n], 0, 0, 0);
      acc[n] = __builtin_amdgcn_mfma_f32_16x16x32_bf16(a1, sfrag[1][n], acc[n], 0, 0, 0);
    }
    float4 mv = *(const float4*)&mb[t0 + (l >> 4) * 4];
    float mr[4] = {mv.x, mv.y, mv.z, mv.w};
#pragma unroll
    for (int r = 0; r < 4; ++r) {
      int t = t0 + (l >> 4) * 4 + r;
      size_t orow = ((size_t)b * T_ + t) * F_ + h * DH_;
#pragma unroll
      for (int n = 0; n < 4; ++n) {
        int dd = n * 16 + (l & 15);
        float w = __expf(acc[n][r] + mr[r]) * iv[n];
        w_out[orow + dd] = w;
        float vval = (float)vb[(size_t)t * NQKV + dd];
        a_pre[orow + dd] = (bf16)(vval * w);
      }
    }
  }
}

// ---------------------------------------------------------------- launch
// ws layout (bytes):
//   qkv  bf16 [65536][2304]  @ 0          (301,989,888)
//   xb   bf16 [65536][768]   @ 301989888  (100,663,296)  -- reused as a_pre
//   WaT  bf16 [2304][768]    @ 402653184  (3,538,944)
//   WpT  bf16 [768][768]     @ 406192128  (1,179,648)
//   Spart f32 [4][384][4096] @ 407371776  (25,165,824)
//   S2b  bf16 [384][4096]    @ 432537600  (3,145,728)
//   total: 435,683,328 B (~416 MB)
extern "C" void kernel_launch(void* const* d_in, const int* in_sizes, int n_in,
                              void* d_out, int out_size, void* d_ws, size_t ws_size,
                              hipStream_t stream) {
  const float* x      = (const float*)d_in[0];
  const float* mask   = (const float*)d_in[1];
  const float* W_attn = (const float*)d_in[2];
  const float* b_attn = (const float*)d_in[3];
  const float* W_proj = (const float*)d_in[4];
  const float* b_proj = (const float*)d_in[5];
  float* out_a = (float*)d_out;
  float* out_w = out_a + (size_t)MTOK * F_;

  char* ws = (char*)d_ws;
  bf16*  qkv   = (bf16*)(ws + 0);
  bf16*  xb    = (bf16*)(ws + 301989888ull);
  bf16*  waT   = (bf16*)(ws + 402653184ull);
  bf16*  wpT   = (bf16*)(ws + 406192128ull);
  float* Spart = (float*)(ws + 407371776ull);
  bf16*  S2b   = (bf16*)(ws + 432537600ull);
  bf16*  a_pre = xb;  // alias: xb dead after gemm1

  k_cast_x<<<24576, 256, 0, stream>>>(x, xb, MTOK * F_ / 8);
  k_tcast<<<dim3(NQKV / 32, F_ / 32), 256, 0, stream>>>(W_attn, waT, F_, NQKV);
  k_tcast<<<dim3(F_ / 32, F_ / 32), 256, 0, stream>>>(W_proj, wpT, F_, F_);
  k_gemm_bt<bf16><<<(MTOK / 128) * (NQKV / 128), 256, 0, stream>>>(
      xb, waT, b_attn, qkv, MTOK, NQKV, F_, MTOK / 128);
  k_stage2_partial<<<B_ * H_ * 4, 256, 0, stream>>>(qkv, Spart);
  k_stage2_finish<<<B_ * H_, 256, 0, stream>>>(Spart, S2b);
  k_stage3<<<B_ * H_, 256, 0, stream>>>(qkv, S2b, mask, out_w, a_pre);
  k_gemm_bt<float><<<(MTOK / 128) * (F_ / 128), 256, 0, stream>>>(
      a_pre, wpT, b_proj, out_a, MTOK, F_, F_, MTOK / 128);
}

// Round 2
// 1168.709 us; speedup vs baseline: 1.0648x; 1.0648x over previous
//
#include <hip/hip_runtime.h>

// Problem constants
#define B_    32
#define T_    2048
#define F_    768
#define H_    12
#define DH_   64
#define MTOK  (B_*T_)     // 65536
#define NQKV  (3*F_)      // 2304

typedef __bf16 bf16;
typedef __bf16 bf16x8 __attribute__((ext_vector_type(8)));
typedef float  f32x4  __attribute__((ext_vector_type(4)));

// ---------------------------------------------------------------- helpers
__device__ __forceinline__ void gload_lds16(const bf16* g, bf16* l) {
  __builtin_amdgcn_global_load_lds(
      (const __attribute__((address_space(1))) unsigned*)g,
      (__attribute__((address_space(3))) unsigned*)l, 16, 0, 0);
}

// ---------------------------------------------------------------- casts
__global__ void k_cast_x(const float* __restrict__ in, bf16* __restrict__ out, int n8) {
  int i = blockIdx.x * 256 + threadIdx.x;
  if (i >= n8) return;
  const float4* p = (const float4*)in + (size_t)i * 2;
  float4 f0 = p[0], f1 = p[1];
  bf16x8 o;
  o[0]=(bf16)f0.x; o[1]=(bf16)f0.y; o[2]=(bf16)f0.z; o[3]=(bf16)f0.w;
  o[4]=(bf16)f1.x; o[5]=(bf16)f1.y; o[6]=(bf16)f1.z; o[7]=(bf16)f1.w;
  *((bf16x8*)out + i) = o;
}

// out[n][k] = (bf16) in[k][n]   (pre-transpose W so GEMM B-tiles stage linearly)
__global__ void k_tcast(const float* __restrict__ in, bf16* __restrict__ out, int K, int N) {
  __shared__ float tile[32][33];
  int n0 = blockIdx.x * 32, k0 = blockIdx.y * 32;
  int tx = threadIdx.x & 31, ty = threadIdx.x >> 5;   // 8 rows, loop 4
#pragma unroll
  for (int r = 0; r < 4; ++r)
    tile[ty + r*8][tx] = in[(size_t)(k0 + ty + r*8) * N + n0 + tx];
  __syncthreads();
#pragma unroll
  for (int r = 0; r < 4; ++r)
    out[(size_t)(n0 + ty + r*8) * K + k0 + tx] = (bf16)tile[tx][ty + r*8];
}

// ---------------------------------------------------------------- m97-style GEMM
// C[M][N] = A[M][K] * Bt[N][K]^T + bias[N].   128x128 tile, BK=32, 4 waves.
// Block order: bn fastest (within each XCD chunk) so each XCD re-reads only
// its own 64-strip of A (196 KB L2-resident) + all of B (3.5 MB, L2/LLC-hit).
template <typename OutT>
__global__ void k_gemm_bt(const bf16* __restrict__ A, const bf16* __restrict__ Bt,
                          const float* __restrict__ bias, OutT* __restrict__ C,
                          int M, int N, int K, int Nt) {
  __shared__ bf16 As[128 * 32];
  __shared__ bf16 Bs[128 * 32];
  int nwg = gridDim.x;
  int bid = blockIdx.x;
  int swz = (bid & 7) * (nwg >> 3) + (bid >> 3);       // XCD swizzle (nwg % 8 == 0)
  int bn = swz % Nt, bm = swz / Nt;                    // bn fastest -> A locality
  int tid = threadIdx.x, wv = tid >> 6, l = tid & 63;
  int wm = (wv >> 1) * 64, wn = (wv & 1) * 64;
  f32x4 acc[4][4] = {};
  const bf16* Ab = A + (size_t)(bm * 128) * K;
  const bf16* Bb = Bt + (size_t)(bn * 128) * K;
  int srow = l >> 2;              // 0..15
  int scol = (l & 3) * 8;
  const int nk = K >> 5;
  for (int kt = 0; kt < nk; ++kt) {
    int k0 = kt * 32;
    __syncthreads();
#pragma unroll
    for (int i = 0; i < 2; ++i) {
      int rr = (i * 4 + wv) * 16 + srow;
      gload_lds16(Ab + (size_t)rr * K + k0 + scol, As + (i * 4 + wv) * 512);
      gload_lds16(Bb + (size_t)rr * K + k0 + scol, Bs + (i * 4 + wv) * 512);
    }
    __syncthreads();
    bf16x8 af[4], bfr[4];
#pragma unroll
    for (int t = 0; t < 4; ++t) {
      af[t]  = *(const bf16x8*)&As[(wm + t * 16 + (l & 15)) * 32 + (l >> 4) * 8];
      bfr[t] = *(const bf16x8*)&Bs[(wn + t * 16 + (l & 15)) * 32 + (l >> 4) * 8];
    }
#pragma unroll
    for (int mi = 0; mi < 4; ++mi)
#pragma unroll
      for (int ni = 0; ni < 4; ++ni)
        acc[mi][ni] = __builtin_amdgcn_mfma_f32_16x16x32_bf16(af[mi], bfr[ni], acc[mi][ni], 0, 0, 0);
  }
#pragma unroll
  for (int ni = 0; ni < 4; ++ni) {
    int col = bn * 128 + wn + ni * 16 + (l & 15);
    float bv = bias[col];
#pragma unroll
    for (int mi = 0; mi < 4; ++mi)
#pragma unroll
      for (int r = 0; r < 4; ++r) {
        int row = bm * 128 + wm + mi * 16 + (l >> 4) * 4 + r;
        C[(size_t)row * N + col] = (OutT)(acc[mi][ni][r] + bv);
      }
  }
}

// ---------------------------------------------------------------- stage 2 (MFMA)
// S[d][e] = sum_t q[t,d] k[t,e] over T=2048, per (b,h). One block per bh,
// 4 waves split t. Fragments gathered directly from global (each load inst =
// 4 rows x 32B coalesced, L1/L2-friendly). Cross-wave reduce in LDS, then
// apply /sqrt(dk), causal mask, /dk^4, cast bf16 -- fused finish.
__global__ __launch_bounds__(256) void k_stage2(const bf16* __restrict__ qkv,
                                                bf16* __restrict__ S2b) {
  int bh = blockIdx.x;
  int b = bh / H_, h = bh % H_;
  int tid = threadIdx.x, wv = tid >> 6, l = tid & 63;
  const bf16* qb = qkv + (size_t)b * T_ * NQKV + h * DH_;
  const bf16* kb = qb + F_;
  f32x4 acc[4][4] = {};
  int tbase = wv * 512 + (l >> 4) * 8;
  int dcol = l & 15;
  for (int kt = 0; kt < 16; ++kt) {
    int t0 = tbase + kt * 32;
    bf16x8 af[4], bfv[4];
#pragma unroll
    for (int j = 0; j < 8; ++j) {
      const bf16* qrow = qb + (size_t)(t0 + j) * NQKV;
      const bf16* krow = kb + (size_t)(t0 + j) * NQKV;
#pragma unroll
      for (int di = 0; di < 4; ++di) {
        af[di][j]  = qrow[di * 16 + dcol];
        bfv[di][j] = krow[di * 16 + dcol];
      }
    }
#pragma unroll
    for (int di = 0; di < 4; ++di)
#pragma unroll
      for (int ej = 0; ej < 4; ++ej)
        acc[di][ej] = __builtin_amdgcn_mfma_f32_16x16x32_bf16(af[di], bfv[ej], acc[di][ej], 0, 0, 0);
  }
  __shared__ float Sred[64][68];   // +4 pad
  for (int w = 0; w < 4; ++w) {
    if (wv == w) {
#pragma unroll
      for (int di = 0; di < 4; ++di)
#pragma unroll
        for (int ej = 0; ej < 4; ++ej)
#pragma unroll
          for (int r = 0; r < 4; ++r) {
            int d = di * 16 + (l >> 4) * 4 + r;
            int e = ej * 16 + dcol;
            if (w == 0) Sred[d][e] = acc[di][ej][r];
            else        Sred[d][e] += acc[di][ej][r];
          }
    }
    __syncthreads();
  }
  const float sc_keep = 0.125f / 16777216.0f;      // (1/sqrt(64)) / 64^4
  const float sc_mask = -10000.0f / 16777216.0f;
  bf16* out = S2b + (size_t)bh * 4096;
  for (int i = tid; i < 4096; i += 256) {
    int d = i >> 6, e = i & 63;
    float v = (e <= d) ? Sred[d][e] * sc_keep : sc_mask;
    out[i] = (bf16)v;
  }
}

// ---------------------------------------------------------------- stage 3
// y[t][d] = sum_e v[t,e] S2[d,e]  (MFMA, A=v, B=S2^T), +mask[b,t], softmax over t
// per d, then w_out (f32) and a_pre = v*w (bf16).  Two-pass recompute, fused.
__global__ __launch_bounds__(256) void k_stage3(const bf16* __restrict__ qkv,
                                                const bf16* __restrict__ S2b,
                                                const float* __restrict__ mask,
                                                float* __restrict__ w_out,
                                                bf16* __restrict__ a_pre) {
  int bh = blockIdx.x;
  int b = bh / H_, h = bh % H_;
  int tid = threadIdx.x, wv = tid >> 6, l = tid & 63;
  const bf16* S2 = S2b + (size_t)bh * 4096;
  bf16x8 sfrag[2][4];
#pragma unroll
  for (int ks = 0; ks < 2; ++ks)
#pragma unroll
    for (int n = 0; n < 4; ++n)
      sfrag[ks][n] = *(const bf16x8*)&S2[(n * 16 + (l & 15)) * 64 + ks * 32 + (l >> 4) * 8];
  const bf16* vb = qkv + (size_t)b * T_ * NQKV + 2 * F_ + h * DH_;
  const float* mb = mask + (size_t)b * T_;
  int t_lo = wv * 512;

  // pass 1: sum of exp per d
  float se[4] = {0.f, 0.f, 0.f, 0.f};
  for (int t0 = t_lo; t0 < t_lo + 512; t0 += 16) {
    f32x4 acc[4] = {};
    bf16x8 a0 = *(const bf16x8*)&vb[(size_t)(t0 + (l & 15)) * NQKV + (l >> 4) * 8];
    bf16x8 a1 = *(const bf16x8*)&vb[(size_t)(t0 + (l & 15)) * NQKV + 32 + (l >> 4) * 8];
#pragma unroll
    for (int n = 0; n < 4; ++n) {
      acc[n] = __builtin_amdgcn_mfma_f32_16x16x32_bf16(a0, sfrag[0][n], acc[n], 0, 0, 0);
      acc[n] = __builtin_amdgcn_mfma_f32_16x16x32_bf16(a1, sfrag[1][n], acc[n], 0, 0, 0);
    }
    float4 mv = *(const float4*)&mb[t0 + (l >> 4) * 4];
    float mr[4] = {mv.x, mv.y, mv.z, mv.w};
#pragma unroll
    for (int n = 0; n < 4; ++n)
#pragma unroll
      for (int r = 0; r < 4; ++r)
        se[n] += __expf(acc[n][r] + mr[r]);
  }
#pragma unroll
  for (int n = 0; n < 4; ++n) {
    se[n] += __shfl_xor(se[n], 16, 64);
    se[n] += __shfl_xor(se[n], 32, 64);
  }
  __shared__ float sred[4][64];
  __shared__ float inv[64];
  if (l < 16) {
#pragma unroll
    for (int n = 0; n < 4; ++n) sred[wv][n * 16 + l] = se[n];
  }
  __syncthreads();
  if (tid < 64) inv[tid] = 1.0f / (sred[0][tid] + sred[1][tid] + sred[2][tid] + sred[3][tid]);
  __syncthreads();
  float iv[4];
#pragma unroll
  for (int n = 0; n < 4; ++n) iv[n] = inv[n * 16 + (l & 15)];

  // pass 2: recompute y, write w and a_pre
  for (int t0 = t_lo; t0 < t_lo + 512; t0 += 16) {
    f32x4 acc[4] = {};
    bf16x8 a0 = *(const bf16x8*)&vb[(size_t)(t0 + (l & 15)) * NQKV + (l >> 4) * 8];
    bf16x8 a1 = *(const bf16x8*)&vb[(size_t)(t0 + (l & 15)) * NQKV + 32 + (l >> 4) * 8];
#pragma unroll
    for (int n = 0; n < 4; ++n) {
      acc[n] = __builtin_amdgcn_mfma_f32_16x16x32_bf16(a0, sfrag[0][n], acc[n], 0, 0, 0);
      acc[n] = __builtin_amdgcn_mfma_f32_16x16x32_bf16(a1, sfrag[1][n], acc[n], 0, 0, 0);
    }
    float4 mv = *(const float4*)&mb[t0 + (l >> 4) * 4];
    float mr[4] = {mv.x, mv.y, mv.z, mv.w};
#pragma unroll
    for (int r = 0; r < 4; ++r) {
      int t = t0 + (l >> 4) * 4 + r;
      size_t orow = ((size_t)b * T_ + t) * F_ + h * DH_;
#pragma unroll
      for (int n = 0; n < 4; ++n) {
        int dd = n * 16 + (l & 15);
        float w = __expf(acc[n][r] + mr[r]) * iv[n];
        w_out[orow + dd] = w;
        float vval = (float)vb[(size_t)t * NQKV + dd];
        a_pre[orow + dd] = (bf16)(vval * w);
      }
    }
  }
}

// ---------------------------------------------------------------- launch
// ws layout (bytes):
//   qkv  bf16 [65536][2304]  @ 0          (301,989,888)
//   xb   bf16 [65536][768]   @ 301989888  (100,663,296)  -- reused as a_pre
//   WaT  bf16 [2304][768]    @ 402653184  (3,538,944)
//   WpT  bf16 [768][768]     @ 406192128  (1,179,648)
//   S2b  bf16 [384][4096]    @ 432537600  (3,145,728)
extern "C" void kernel_launch(void* const* d_in, const int* in_sizes, int n_in,
                              void* d_out, int out_size, void* d_ws, size_t ws_size,
                              hipStream_t stream) {
  const float* x      = (const float*)d_in[0];
  const float* mask   = (const float*)d_in[1];
  const float* W_attn = (const float*)d_in[2];
  const float* b_attn = (const float*)d_in[3];
  const float* W_proj = (const float*)d_in[4];
  const float* b_proj = (const float*)d_in[5];
  float* out_a = (float*)d_out;
  float* out_w = out_a + (size_t)MTOK * F_;

  char* ws = (char*)d_ws;
  bf16*  qkv   = (bf16*)(ws + 0);
  bf16*  xb    = (bf16*)(ws + 301989888ull);
  bf16*  waT   = (bf16*)(ws + 402653184ull);
  bf16*  wpT   = (bf16*)(ws + 406192128ull);
  bf16*  S2b   = (bf16*)(ws + 432537600ull);
  bf16*  a_pre = xb;  // alias: xb dead after gemm1

  k_cast_x<<<24576, 256, 0, stream>>>(x, xb, MTOK * F_ / 8);
  k_tcast<<<dim3(NQKV / 32, F_ / 32), 256, 0, stream>>>(W_attn, waT, F_, NQKV);
  k_tcast<<<dim3(F_ / 32, F_ / 32), 256, 0, stream>>>(W_proj, wpT, F_, F_);
  k_gemm_bt<bf16><<<(MTOK / 128) * (NQKV / 128), 256, 0, stream>>>(
      xb, waT, b_attn, qkv, MTOK, NQKV, F_, NQKV / 128);
  k_stage2<<<B_ * H_, 256, 0, stream>>>(qkv, S2b);
  k_stage3<<<B_ * H_, 256, 0, stream>>>(qkv, S2b, mask, out_w, a_pre);
  k_gemm_bt<float><<<(MTOK / 128) * (F_ / 128), 256, 0, stream>>>(
      a_pre, wpT, b_proj, out_a, MTOK, F_, F_, F_ / 128);
}

// Round 3
// 1144.940 us; speedup vs baseline: 1.0869x; 1.0208x over previous
//
#include <hip/hip_runtime.h>

// Problem constants
#define B_    32
#define T_    2048
#define F_    768
#define H_    12
#define DH_   64
#define MTOK  (B_*T_)     // 65536
#define NQKV  (3*F_)      // 2304
#define MTP   65600       // padded qT/kT row stride (breaks 128KB power-of-2 aliasing)

typedef __bf16 bf16;
typedef __bf16 bf16x4 __attribute__((ext_vector_type(4)));
typedef __bf16 bf16x8 __attribute__((ext_vector_type(8)));
typedef float  f32x4  __attribute__((ext_vector_type(4)));

// ---------------------------------------------------------------- helpers
__device__ __forceinline__ void gload_lds16(const bf16* g, bf16* l) {
  __builtin_amdgcn_global_load_lds(
      (const __attribute__((address_space(1))) unsigned*)g,
      (__attribute__((address_space(3))) unsigned*)l, 16, 0, 0);
}

// ---------------------------------------------------------------- casts
__global__ void k_cast_x(const float* __restrict__ in, bf16* __restrict__ out, int n8) {
  int i = blockIdx.x * 256 + threadIdx.x;
  if (i >= n8) return;
  const float4* p = (const float4*)in + (size_t)i * 2;
  float4 f0 = p[0], f1 = p[1];
  bf16x8 o;
  o[0]=(bf16)f0.x; o[1]=(bf16)f0.y; o[2]=(bf16)f0.z; o[3]=(bf16)f0.w;
  o[4]=(bf16)f1.x; o[5]=(bf16)f1.y; o[6]=(bf16)f1.z; o[7]=(bf16)f1.w;
  *((bf16x8*)out + i) = o;
}

// out[n][k] = (bf16) in[k][n]   (pre-transpose W so GEMM B-tiles stage linearly)
__global__ void k_tcast(const float* __restrict__ in, bf16* __restrict__ out, int K, int N) {
  __shared__ float tile[32][33];
  int n0 = blockIdx.x * 32, k0 = blockIdx.y * 32;
  int tx = threadIdx.x & 31, ty = threadIdx.x >> 5;
#pragma unroll
  for (int r = 0; r < 4; ++r)
    tile[ty + r*8][tx] = in[(size_t)(k0 + ty + r*8) * N + n0 + tx];
  __syncthreads();
#pragma unroll
  for (int r = 0; r < 4; ++r)
    out[(size_t)(n0 + ty + r*8) * K + k0 + tx] = (bf16)tile[tx][ty + r*8];
}

// ---------------------------------------------------------------- GEMM1 (QKV, split outputs)
// qkv = xb @ waT^T + b_attn.  cols 0..767 -> qT[col][row] (transposed),
// 768..1535 -> kT[col-768][row], 1536..2303 -> v[row][col-1536] row-major.
__global__ void k_gemm_qkv(const bf16* __restrict__ A, const bf16* __restrict__ Bt,
                           const float* __restrict__ bias,
                           bf16* __restrict__ qT, bf16* __restrict__ kT,
                           bf16* __restrict__ vout) {
  const int K = F_;
  __shared__ bf16 As[128 * 32];
  __shared__ bf16 Bs[128 * 32];
  int nwg = gridDim.x;
  int bid = blockIdx.x;
  int swz = (bid & 7) * (nwg >> 3) + (bid >> 3);
  int bn = swz % 18, bm = swz / 18;                    // bn fastest -> A locality
  int tid = threadIdx.x, wv = tid >> 6, l = tid & 63;
  int wm = (wv >> 1) * 64, wn = (wv & 1) * 64;
  f32x4 acc[4][4] = {};
  const bf16* Ab = A + (size_t)(bm * 128) * K;
  const bf16* Bb = Bt + (size_t)(bn * 128) * K;
  int srow = l >> 2, scol = (l & 3) * 8;
  for (int kt = 0; kt < 24; ++kt) {
    int k0 = kt * 32;
    __syncthreads();
#pragma unroll
    for (int i = 0; i < 2; ++i) {
      int rr = (i * 4 + wv) * 16 + srow;
      gload_lds16(Ab + (size_t)rr * K + k0 + scol, As + (i * 4 + wv) * 512);
      gload_lds16(Bb + (size_t)rr * K + k0 + scol, Bs + (i * 4 + wv) * 512);
    }
    __syncthreads();
    bf16x8 af[4], bfr[4];
#pragma unroll
    for (int t = 0; t < 4; ++t) {
      af[t]  = *(const bf16x8*)&As[(wm + t * 16 + (l & 15)) * 32 + (l >> 4) * 8];
      bfr[t] = *(const bf16x8*)&Bs[(wn + t * 16 + (l & 15)) * 32 + (l >> 4) * 8];
    }
#pragma unroll
    for (int mi = 0; mi < 4; ++mi)
#pragma unroll
      for (int ni = 0; ni < 4; ++ni)
        acc[mi][ni] = __builtin_amdgcn_mfma_f32_16x16x32_bf16(af[mi], bfr[ni], acc[mi][ni], 0, 0, 0);
  }
#pragma unroll
  for (int ni = 0; ni < 4; ++ni) {
    int col = bn * 128 + wn + ni * 16 + (l & 15);
    float bv = bias[col];
    if (col < 1536) {                                  // wave-uniform (tile-aligned)
      bf16* rp = (col < 768) ? (qT + (size_t)col * MTP)
                             : (kT + (size_t)(col - 768) * MTP);
#pragma unroll
      for (int mi = 0; mi < 4; ++mi) {
        int row0 = bm * 128 + wm + mi * 16 + (l >> 4) * 4;
        bf16x4 o;
#pragma unroll
        for (int r = 0; r < 4; ++r) o[r] = (bf16)(acc[mi][ni][r] + bv);
        *(bf16x4*)&rp[row0] = o;
      }
    } else {
      int vc = col - 1536;
#pragma unroll
      for (int mi = 0; mi < 4; ++mi)
#pragma unroll
        for (int r = 0; r < 4; ++r) {
          int row = bm * 128 + wm + mi * 16 + (l >> 4) * 4 + r;
          vout[(size_t)row * F_ + vc] = (bf16)(acc[mi][ni][r] + bv);
        }
    }
  }
}

// ---------------------------------------------------------------- GEMM2 (proj)
// C[M][N] = A[M][K] * Bt[N][K]^T + bias[N].   128x128 tile, BK=32, 4 waves.
__global__ void k_gemm_bt(const bf16* __restrict__ A, const bf16* __restrict__ Bt,
                          const float* __restrict__ bias, float* __restrict__ C,
                          int M, int N, int K, int Nt) {
  __shared__ bf16 As[128 * 32];
  __shared__ bf16 Bs[128 * 32];
  int nwg = gridDim.x;
  int bid = blockIdx.x;
  int swz = (bid & 7) * (nwg >> 3) + (bid >> 3);
  int bn = swz % Nt, bm = swz / Nt;
  int tid = threadIdx.x, wv = tid >> 6, l = tid & 63;
  int wm = (wv >> 1) * 64, wn = (wv & 1) * 64;
  f32x4 acc[4][4] = {};
  const bf16* Ab = A + (size_t)(bm * 128) * K;
  const bf16* Bb = Bt + (size_t)(bn * 128) * K;
  int srow = l >> 2, scol = (l & 3) * 8;
  const int nk = K >> 5;
  for (int kt = 0; kt < nk; ++kt) {
    int k0 = kt * 32;
    __syncthreads();
#pragma unroll
    for (int i = 0; i < 2; ++i) {
      int rr = (i * 4 + wv) * 16 + srow;
      gload_lds16(Ab + (size_t)rr * K + k0 + scol, As + (i * 4 + wv) * 512);
      gload_lds16(Bb + (size_t)rr * K + k0 + scol, Bs + (i * 4 + wv) * 512);
    }
    __syncthreads();
    bf16x8 af[4], bfr[4];
#pragma unroll
    for (int t = 0; t < 4; ++t) {
      af[t]  = *(const bf16x8*)&As[(wm + t * 16 + (l & 15)) * 32 + (l >> 4) * 8];
      bfr[t] = *(const bf16x8*)&Bs[(wn + t * 16 + (l & 15)) * 32 + (l >> 4) * 8];
    }
#pragma unroll
    for (int mi = 0; mi < 4; ++mi)
#pragma unroll
      for (int ni = 0; ni < 4; ++ni)
        acc[mi][ni] = __builtin_amdgcn_mfma_f32_16x16x32_bf16(af[mi], bfr[ni], acc[mi][ni], 0, 0, 0);
  }
#pragma unroll
  for (int ni = 0; ni < 4; ++ni) {
    int col = bn * 128 + wn + ni * 16 + (l & 15);
    float bv = bias[col];
#pragma unroll
    for (int mi = 0; mi < 4; ++mi)
#pragma unroll
      for (int r = 0; r < 4; ++r) {
        int row = bm * 128 + wm + mi * 16 + (l >> 4) * 4 + r;
        C[(size_t)row * N + col] = acc[mi][ni][r] + bv;
      }
  }
}

// ---------------------------------------------------------------- stage 2 (MFMA from qT/kT)
// S[d][e] = sum_t q[t,d] k[t,e] per (b,h). One 1024-thread block per bh,
// 16 waves x 128 t-rows each, contiguous bf16x8 fragment loads, sequential
// LDS reduce, fused mask/scale/cast.
__global__ __launch_bounds__(1024) void k_stage2(const bf16* __restrict__ qT,
                                                 const bf16* __restrict__ kT,
                                                 bf16* __restrict__ S2b) {
  int bh = blockIdx.x;
  int b = bh / H_, h = bh % H_;
  int tid = threadIdx.x, wv = tid >> 6, l = tid & 63;
  const bf16* qb = qT + (size_t)(h * DH_) * MTP + b * T_;
  const bf16* kb = kT + (size_t)(h * DH_) * MTP + b * T_;
  f32x4 acc[4][4] = {};
  for (int kt = 0; kt < 4; ++kt) {
    int t0 = wv * 128 + kt * 32 + (l >> 4) * 8;
    bf16x8 af[4], bfv[4];
#pragma unroll
    for (int di = 0; di < 4; ++di) {
      af[di]  = *(const bf16x8*)&qb[(size_t)(di * 16 + (l & 15)) * MTP + t0];
      bfv[di] = *(const bf16x8*)&kb[(size_t)(di * 16 + (l & 15)) * MTP + t0];
    }
#pragma unroll
    for (int di = 0; di < 4; ++di)
#pragma unroll
      for (int ej = 0; ej < 4; ++ej)
        acc[di][ej] = __builtin_amdgcn_mfma_f32_16x16x32_bf16(af[di], bfv[ej], acc[di][ej], 0, 0, 0);
  }
  __shared__ float Sred[64][68];
  for (int w = 0; w < 16; ++w) {
    if (wv == w) {
#pragma unroll
      for (int di = 0; di < 4; ++di)
#pragma unroll
        for (int ej = 0; ej < 4; ++ej)
#pragma unroll
          for (int r = 0; r < 4; ++r) {
            int d = di * 16 + (l >> 4) * 4 + r;
            int e = ej * 16 + (l & 15);
            if (w == 0) Sred[d][e] = acc[di][ej][r];
            else        Sred[d][e] += acc[di][ej][r];
          }
    }
    __syncthreads();
  }
  const float sc_keep = 0.125f / 16777216.0f;      // (1/sqrt(64)) / 64^4
  const float sc_mask = -10000.0f / 16777216.0f;
  bf16* out = S2b + (size_t)bh * 4096;
  for (int i = tid; i < 4096; i += 1024) {
    int d = i >> 6, e = i & 63;
    out[i] = (bf16)((e <= d) ? Sred[d][e] * sc_keep : sc_mask);
  }
}

// ---------------------------------------------------------------- stage 3
// y[t][d] = sum_e v[t,e] S2[d,e] (MFMA), +mask, softmax over t per d,
// w_out (f32) and a_pre = v*w (bf16).  16 waves x 128 t, two-pass recompute.
__global__ __launch_bounds__(1024) void k_stage3(const bf16* __restrict__ v,
                                                 const bf16* __restrict__ S2b,
                                                 const float* __restrict__ mask,
                                                 float* __restrict__ w_out,
                                                 bf16* __restrict__ a_pre) {
  int bh = blockIdx.x;
  int b = bh / H_, h = bh % H_;
  int tid = threadIdx.x, wv = tid >> 6, l = tid & 63;
  const bf16* S2 = S2b + (size_t)bh * 4096;
  bf16x8 sfrag[2][4];
#pragma unroll
  for (int ks = 0; ks < 2; ++ks)
#pragma unroll
    for (int n = 0; n < 4; ++n)
      sfrag[ks][n] = *(const bf16x8*)&S2[(n * 16 + (l & 15)) * 64 + ks * 32 + (l >> 4) * 8];
  const bf16* vb = v + (size_t)b * T_ * F_ + h * DH_;
  const float* mb = mask + (size_t)b * T_;
  int t_lo = wv * 128;

  // pass 1: sum of exp per d
  float se[4] = {0.f, 0.f, 0.f, 0.f};
  for (int t0 = t_lo; t0 < t_lo + 128; t0 += 16) {
    f32x4 acc[4] = {};
    bf16x8 a0 = *(const bf16x8*)&vb[(size_t)(t0 + (l & 15)) * F_ + (l >> 4) * 8];
    bf16x8 a1 = *(const bf16x8*)&vb[(size_t)(t0 + (l & 15)) * F_ + 32 + (l >> 4) * 8];
#pragma unroll
    for (int n = 0; n < 4; ++n) {
      acc[n] = __builtin_amdgcn_mfma_f32_16x16x32_bf16(a0, sfrag[0][n], acc[n], 0, 0, 0);
      acc[n] = __builtin_amdgcn_mfma_f32_16x16x32_bf16(a1, sfrag[1][n], acc[n], 0, 0, 0);
    }
    float4 mv = *(const float4*)&mb[t0 + (l >> 4) * 4];
    float mr[4] = {mv.x, mv.y, mv.z, mv.w};
#pragma unroll
    for (int n = 0; n < 4; ++n)
#pragma unroll
      for (int r = 0; r < 4; ++r)
        se[n] += __expf(acc[n][r] + mr[r]);
  }
#pragma unroll
  for (int n = 0; n < 4; ++n) {
    se[n] += __shfl_xor(se[n], 16, 64);
    se[n] += __shfl_xor(se[n], 32, 64);
  }
  __shared__ float sred[16][64];
  __shared__ float inv[64];
  if (l < 16) {
#pragma unroll
    for (int n = 0; n < 4; ++n) sred[wv][n * 16 + l] = se[n];
  }
  __syncthreads();
  if (tid < 64) {
    float s = 0.f;
#pragma unroll
    for (int w = 0; w < 16; ++w) s += sred[w][tid];
    inv[tid] = 1.0f / s;
  }
  __syncthreads();
  float iv[4];
#pragma unroll
  for (int n = 0; n < 4; ++n) iv[n] = inv[n * 16 + (l & 15)];

  // pass 2: recompute y, write w and a_pre
  for (int t0 = t_lo; t0 < t_lo + 128; t0 += 16) {
    f32x4 acc[4] = {};
    bf16x8 a0 = *(const bf16x8*)&vb[(size_t)(t0 + (l & 15)) * F_ + (l >> 4) * 8];
    bf16x8 a1 = *(const bf16x8*)&vb[(size_t)(t0 + (l & 15)) * F_ + 32 + (l >> 4) * 8];
#pragma unroll
    for (int n = 0; n < 4; ++n) {
      acc[n] = __builtin_amdgcn_mfma_f32_16x16x32_bf16(a0, sfrag[0][n], acc[n], 0, 0, 0);
      acc[n] = __builtin_amdgcn_mfma_f32_16x16x32_bf16(a1, sfrag[1][n], acc[n], 0, 0, 0);
    }
    float4 mv = *(const float4*)&mb[t0 + (l >> 4) * 4];
    float mr[4] = {mv.x, mv.y, mv.z, mv.w};
#pragma unroll
    for (int r = 0; r < 4; ++r) {
      int t = t0 + (l >> 4) * 4 + r;
      size_t orow = ((size_t)b * T_ + t) * F_ + h * DH_;
#pragma unroll
      for (int n = 0; n < 4; ++n) {
        int dd = n * 16 + (l & 15);
        float w = __expf(acc[n][r] + mr[r]) * iv[n];
        w_out[orow + dd] = w;
        float vval = (float)vb[(size_t)t * F_ + dd];
        a_pre[orow + dd] = (bf16)(vval * w);
      }
    }
  }
}

// ---------------------------------------------------------------- launch
// ws layout (bytes):
//   xb   bf16 [65536][768]  @ 0           (100,663,296)  -- reused as a_pre
//   qT   bf16 [768][65600]  @ 100663296   (100,761,600)
//   kT   bf16 [768][65600]  @ 201424896   (100,761,600)
//   v    bf16 [65536][768]  @ 302186496   (100,663,296)
//   waT  bf16 [2304][768]   @ 402849792   (3,538,944)
//   wpT  bf16 [768][768]    @ 406388736   (1,179,648)
//   S2b  bf16 [384][4096]   @ 407568384   (3,145,728)   total 410,714,112
extern "C" void kernel_launch(void* const* d_in, const int* in_sizes, int n_in,
                              void* d_out, int out_size, void* d_ws, size_t ws_size,
                              hipStream_t stream) {
  const float* x      = (const float*)d_in[0];
  const float* mask   = (const float*)d_in[1];
  const float* W_attn = (const float*)d_in[2];
  const float* b_attn = (const float*)d_in[3];
  const float* W_proj = (const float*)d_in[4];
  const float* b_proj = (const float*)d_in[5];
  float* out_a = (float*)d_out;
  float* out_w = out_a + (size_t)MTOK * F_;

  char* ws = (char*)d_ws;
  bf16* xb  = (bf16*)(ws + 0);
  bf16* qT  = (bf16*)(ws + 100663296ull);
  bf16* kT  = (bf16*)(ws + 201424896ull);
  bf16* v   = (bf16*)(ws + 302186496ull);
  bf16* waT = (bf16*)(ws + 402849792ull);
  bf16* wpT = (bf16*)(ws + 406388736ull);
  bf16* S2b = (bf16*)(ws + 407568384ull);
  bf16* a_pre = xb;  // alias: xb dead after gemm1

  k_cast_x<<<24576, 256, 0, stream>>>(x, xb, MTOK * F_ / 8);
  k_tcast<<<dim3(NQKV / 32, F_ / 32), 256, 0, stream>>>(W_attn, waT, F_, NQKV);
  k_tcast<<<dim3(F_ / 32, F_ / 32), 256, 0, stream>>>(W_proj, wpT, F_, F_);
  k_gemm_qkv<<<(MTOK / 128) * (NQKV / 128), 256, 0, stream>>>(
      xb, waT, b_attn, qT, kT, v);
  k_stage2<<<B_ * H_, 1024, 0, stream>>>(qT, kT, S2b);
  k_stage3<<<B_ * H_, 1024, 0, stream>>>(v, S2b, mask, out_w, a_pre);
  k_gemm_bt<<<(MTOK / 128) * (F_ / 128), 256, 0, stream>>>(
      a_pre, wpT, b_proj, out_a, MTOK, F_, F_, F_ / 128);
}